// Round 2
// baseline (658.111 us; speedup 1.0000x reference)
//
#include <hip/hip_runtime.h>

#define NROWS 8192
#define BBND  32
#define CBND  512

typedef unsigned short u16;
typedef __bf16 bf16x8 __attribute__((ext_vector_type(8)));
typedef float  f32x4  __attribute__((ext_vector_type(4)));

static __device__ inline u16 f2bf(float f) {
    unsigned u = __builtin_bit_cast(unsigned, f);
    unsigned r = (u + 0x7FFFu + ((u >> 16) & 1u)) >> 16;
    return (u16)r;
}

static __device__ inline float pow14(float base) {
    // base^1.4 = exp2(1.4*log2(base)); base >= 0. base==0 -> exp2(-inf) = 0.
    return __builtin_amdgcn_exp2f(1.4f * __builtin_amdgcn_logf(base));
}

static __device__ inline float sigmoidf_fast(float v) {
    // 1/(1+exp(-v)) via exp2
    float e = __builtin_amdgcn_exp2f(-1.44269504f * v);
    return 1.f / (1.f + e);
}

// ---------------- prep: row sums of bbn + bf16 copy ----------------
__global__ __launch_bounds__(256) void k_prep_rows(const float* __restrict__ bbn,
                                                   float* __restrict__ s,
                                                   u16* __restrict__ bbn_bf) {
    int i = blockIdx.x * 256 + threadIdx.x;
    if (i >= NROWS) return;
    const f32x4* row = reinterpret_cast<const f32x4*>(bbn + i * BBND);
    float sum = 0.f;
    u16* dst = bbn_bf + i * BBND;
#pragma unroll
    for (int q = 0; q < 8; ++q) {
        f32x4 v = row[q];
#pragma unroll
        for (int e = 0; e < 4; ++e) {
            sum += v[e];
            dst[q * 4 + e] = f2bf(v[e]);
        }
    }
    s[i] = sum;
}

// ---------------- prep: W transpose -> bf16 ----------------
__global__ __launch_bounds__(256) void k_prep_wt(const float* __restrict__ W,
                                                 u16* __restrict__ WT) {
    int idx = blockIdx.x * 256 + threadIdx.x;   // over 512*512
    int c = idx >> 9, k = idx & 511;
    WT[idx] = f2bf(W[k * CBND + c]);            // WT[c][k]
}

// ---------------- degree: d_i = sum_j adj_ij ; dinv = rsqrt(d+eps) ----------------
__global__ __launch_bounds__(256) void k_deg(const u16* __restrict__ bbn_bf,
                                             const float* __restrict__ s,
                                             float* __restrict__ dinv) {
    __shared__ float part[4][16];
    int ibase = blockIdx.x * 16;                 // 512 blocks, 16 rows each
    int tid = threadIdx.x;
    int w = tid >> 6, l = tid & 63, lg = l >> 4, lr = l & 15;

    bf16x8 afrag = *reinterpret_cast<const bf16x8*>(bbn_bf + (ibase + lr) * BBND + lg * 8);
    float si[4];
#pragma unroll
    for (int r = 0; r < 4; ++r) si[r] = s[ibase + lg * 4 + r];

    float dacc[4] = {0.f, 0.f, 0.f, 0.f};
    int j0 = w * (NROWS / 4);
    for (int jt = 0; jt < NROWS / 4; jt += 16) {
        int jb = j0 + jt;
        bf16x8 bfrag = *reinterpret_cast<const bf16x8*>(bbn_bf + (jb + lr) * BBND + lg * 8);
        f32x4 dot = __builtin_amdgcn_mfma_f32_16x16x32_bf16(afrag, bfrag,
                     (f32x4){0.f, 0.f, 0.f, 0.f}, 0, 0, 0);
        float sj = s[jb + lr];
#pragma unroll
        for (int r = 0; r < 4; ++r) {
            float nd = fabsf(2.f * dot[r] - si[r] - sj) * (1.f / 32.f);
            float base = fmaxf(1.f - nd, 0.f);
            dacc[r] += pow14(base);
        }
    }
#pragma unroll
    for (int off = 1; off < 16; off <<= 1)
#pragma unroll
        for (int r = 0; r < 4; ++r) dacc[r] += __shfl_xor(dacc[r], off, 64);

    if (lr == 0) {
#pragma unroll
        for (int r = 0; r < 4; ++r) part[w][lg * 4 + r] = dacc[r];
    }
    __syncthreads();
    if (tid < 16) {
        float d = part[0][tid] + part[1][tid] + part[2][tid] + part[3][tid];
        dinv[ibase + tid] = rsqrtf(d + 1e-8f);
    }
}

// ---------------- fc: gT[c][j] = dinv_j * (cbn@W + b)[j][c], bf16 ----------------
__global__ __launch_bounds__(256) void k_fc(const float* __restrict__ cbn,
                                            const u16* __restrict__ WT,
                                            const float* __restrict__ bvec,
                                            const float* __restrict__ dinv,
                                            u16* __restrict__ gT) {
    int bid = blockIdx.x;            // 1024 = 128 j-tiles * 8 c-tiles
    int cb = bid & 7, jb = bid >> 3;
    int tid = threadIdx.x, w = tid >> 6, l = tid & 63, lg = l >> 4, lr = l & 15;
    int crow = cb * 64 + w * 16;
    int jcol = jb * 64;

    f32x4 acc[4];
#pragma unroll
    for (int f = 0; f < 4; ++f) acc[f] = (f32x4){0.f, 0.f, 0.f, 0.f};

    for (int k0 = 0; k0 < CBND; k0 += 32) {
        bf16x8 afrag = *reinterpret_cast<const bf16x8*>(WT + (crow + lr) * CBND + k0 + lg * 8);
#pragma unroll
        for (int f = 0; f < 4; ++f) {
            const float* src = cbn + (jcol + f * 16 + lr) * CBND + k0 + lg * 8;
            f32x4 v0 = *reinterpret_cast<const f32x4*>(src);
            f32x4 v1 = *reinterpret_cast<const f32x4*>(src + 4);
            bf16x8 bfrag;
#pragma unroll
            for (int e = 0; e < 4; ++e) { bfrag[e] = (__bf16)v0[e]; bfrag[e + 4] = (__bf16)v1[e]; }
            acc[f] = __builtin_amdgcn_mfma_f32_16x16x32_bf16(afrag, bfrag, acc[f], 0, 0, 0);
        }
    }
#pragma unroll
    for (int f = 0; f < 4; ++f) {
#pragma unroll
        for (int r = 0; r < 4; ++r) {
            int c = crow + lg * 4 + r;
            int j = jcol + f * 16 + lr;
            float val = acc[f][r] + bvec[c];
            gT[c * NROWS + j] = f2bf(val * dinv[j]);
        }
    }
}

// ---------------- conv: out = sigmoid(dinv_i * sum_j adj_ij * gT[:,j]) ----------------
__global__ __launch_bounds__(512) void k_conv(const u16* __restrict__ bbn_bf,
                                              const float* __restrict__ s,
                                              const float* __restrict__ dinv,
                                              const u16* __restrict__ gT,
                                              float* __restrict__ out) {
    __shared__ __align__(16) u16 Alds[64 * 32];
    int bid = blockIdx.x;            // 256 = 128 i-tiles * 2 c-halves
    int ib = bid >> 1, cb = bid & 1;
    int tid = threadIdx.x, w = tid >> 6, l = tid & 63, lg = l >> 4, lr = l & 15;
    int wm = w >> 1, wn = w & 1;
    int ibase = ib * 64;
    int cbase = cb * 256 + wn * 128;

    // adj generation operands: wave (wm,wn) generates quadrant rows wm*16, cols wn*16 of the 64x32 tile
    bf16x8 genA = *reinterpret_cast<const bf16x8*>(bbn_bf + (ibase + wm * 16 + lr) * BBND + lg * 8);
    float si[4];
#pragma unroll
    for (int r = 0; r < 4; ++r) si[r] = s[ibase + wm * 16 + lg * 4 + r];

    f32x4 acc[8];
#pragma unroll
    for (int f = 0; f < 8; ++f) acc[f] = (f32x4){0.f, 0.f, 0.f, 0.f};

    for (int j0 = 0; j0 < NROWS; j0 += 32) {
        // --- generate adj quadrant (16x16) via dot-MFMA ---
        int jq = j0 + wn * 16;
        bf16x8 genB = *reinterpret_cast<const bf16x8*>(bbn_bf + (jq + lr) * BBND + lg * 8);
        f32x4 dot = __builtin_amdgcn_mfma_f32_16x16x32_bf16(genA, genB,
                     (f32x4){0.f, 0.f, 0.f, 0.f}, 0, 0, 0);
        float sj = s[jq + lr];
#pragma unroll
        for (int r = 0; r < 4; ++r) {
            float nd = fabsf(2.f * dot[r] - si[r] - sj) * (1.f / 32.f);
            float base = fmaxf(1.f - nd, 0.f);
            float adj = pow14(base);
            Alds[(wm * 16 + lg * 4 + r) * 32 + wn * 16 + lr] = f2bf(adj);
        }
        __syncthreads();
        // --- big MFMA: A = adj tile (rows=i, K=j 32), B = gT (K=j, cols=c) ---
        bf16x8 af = *reinterpret_cast<const bf16x8*>(&Alds[(wm * 16 + lr) * 32 + lg * 8]);
#pragma unroll
        for (int f = 0; f < 8; ++f) {
            bf16x8 bfr = *reinterpret_cast<const bf16x8*>(gT + (cbase + f * 16 + lr) * NROWS + j0 + lg * 8);
            acc[f] = __builtin_amdgcn_mfma_f32_16x16x32_bf16(af, bfr, acc[f], 0, 0, 0);
        }
        __syncthreads();
    }
#pragma unroll
    for (int r = 0; r < 4; ++r) {
        int irow = ibase + wm * 16 + lg * 4 + r;
        float di = dinv[irow];
#pragma unroll
        for (int f = 0; f < 8; ++f) {
            int ccol = cbase + f * 16 + lr;
            float v = acc[f][r] * di;
            out[irow * CBND + ccol] = sigmoidf_fast(v);
        }
    }
}

extern "C" void kernel_launch(void* const* d_in, const int* in_sizes, int n_in,
                              void* d_out, int out_size, void* d_ws, size_t ws_size,
                              hipStream_t stream) {
    const float* bbn = (const float*)d_in[0];   // [8192,32]
    const float* cbn = (const float*)d_in[1];   // [8192,512]
    const float* W   = (const float*)d_in[2];   // [512,512]
    const float* b   = (const float*)d_in[3];   // [512]
    float* out = (float*)d_out;                 // [8192,512] f32

    char* ws = (char*)d_ws;
    float* s      = (float*)ws;  ws += NROWS * 4;
    float* dinv   = (float*)ws;  ws += NROWS * 4;
    u16* bbn_bf   = (u16*)ws;    ws += NROWS * BBND * 2;
    u16* WT       = (u16*)ws;    ws += CBND * CBND * 2;
    u16* gT       = (u16*)ws;    ws += CBND * NROWS * 2;

    k_prep_rows<<<NROWS / 256, 256, 0, stream>>>(bbn, s, bbn_bf);
    k_prep_wt<<<(CBND * CBND) / 256, 256, 0, stream>>>(W, WT);
    k_deg<<<NROWS / 16, 256, 0, stream>>>(bbn_bf, s, dinv);
    k_fc<<<(NROWS / 64) * (CBND / 64), 256, 0, stream>>>(cbn, WT, b, dinv, gT);
    k_conv<<<(NROWS / 64) * 2, 512, 0, stream>>>(bbn_bf, s, dinv, gT, out);
}

// Round 3
// 250.381 us; speedup vs baseline: 2.6284x; 2.6284x over previous
//
#include <hip/hip_runtime.h>

#define NROWS 8192
#define BBND  32
#define CBND  512
#define JSTEP 64
#define NT (NROWS / JSTEP)   // 128
#define ABUF (64 * 144)      // bytes per A LDS buffer (64 rows x 72 elems x 2B)
#define BBUF 16384           // bytes per B LDS buffer (128c x 64j x 2B)

typedef unsigned short u16;
typedef unsigned int   u32;
typedef __bf16 bf16x8 __attribute__((ext_vector_type(8)));
typedef float  f32x4  __attribute__((ext_vector_type(4)));
typedef u32    u32x4  __attribute__((ext_vector_type(4)));
typedef u32    u32x2  __attribute__((ext_vector_type(2)));

static __device__ inline u16 f2bf(float f) {
    unsigned u = __builtin_bit_cast(unsigned, f);
    unsigned r = (u + 0x7FFFu + ((u >> 16) & 1u)) >> 16;
    return (u16)r;
}

static __device__ inline float pow14(float base) {
    return __builtin_amdgcn_exp2f(1.4f * __builtin_amdgcn_logf(base));
}

static __device__ inline float adj_eval(float dot, float sij) {
    float x = fabsf(2.f * dot - sij);
    float base = fmaxf(1.f - x * (1.f / 32.f), 0.f);
    return pow14(base);
}

static __device__ inline float sigmoidf_fast(float v) {
    float e = __builtin_amdgcn_exp2f(-1.44269504f * v);
    return 1.f / (1.f + e);
}

static __device__ inline u32 cvtpk(float a, float b) {
    u32 r;
    asm("v_cvt_pk_bf16_f32 %0, %1, %2" : "=v"(r) : "v"(a), "v"(b));
    return r;
}

static __device__ inline f32x4 MFMA(bf16x8 a, bf16x8 b, f32x4 c) {
    return __builtin_amdgcn_mfma_f32_16x16x32_bf16(a, b, c, 0, 0, 0);
}

// ---------------- prep: row sums of bbn + bf16 copy ----------------
__global__ __launch_bounds__(256) void k_prep_rows(const float* __restrict__ bbn,
                                                   float* __restrict__ s,
                                                   u16* __restrict__ bbn_bf) {
    int i = blockIdx.x * 256 + threadIdx.x;
    if (i >= NROWS) return;
    const f32x4* row = reinterpret_cast<const f32x4*>(bbn + i * BBND);
    float sum = 0.f;
    u16* dst = bbn_bf + i * BBND;
#pragma unroll
    for (int q = 0; q < 8; ++q) {
        f32x4 v = row[q];
#pragma unroll
        for (int e = 0; e < 4; ++e) {
            sum += v[e];
            dst[q * 4 + e] = f2bf(v[e]);
        }
    }
    s[i] = sum;
}

// ---------------- prep: W transpose -> bf16 ----------------
__global__ __launch_bounds__(256) void k_prep_wt(const float* __restrict__ W,
                                                 u16* __restrict__ WT) {
    int idx = blockIdx.x * 256 + threadIdx.x;   // over 512*512
    int c = idx >> 9, k = idx & 511;
    WT[idx] = f2bf(W[k * CBND + c]);            // WT[c][k]
}

// ---------------- degree: d_i = sum_j adj_ij ; dinv = rsqrt(d+eps) ----------------
__global__ __launch_bounds__(512) void k_deg(const u16* __restrict__ bbn_bf,
                                             const float* __restrict__ s,
                                             float* __restrict__ dinv) {
    __shared__ float part[8][16];
    int ibase = blockIdx.x * 16;                 // 512 blocks, 16 rows each
    int tid = threadIdx.x;
    int w = tid >> 6, l = tid & 63, lg = l >> 4, lr = l & 15;

    bf16x8 afrag = *reinterpret_cast<const bf16x8*>(bbn_bf + (ibase + lr) * BBND + lg * 8);
    float si[4];
#pragma unroll
    for (int r = 0; r < 4; ++r) si[r] = s[ibase + lg * 4 + r];

    float dacc[4] = {0.f, 0.f, 0.f, 0.f};
    int j0 = w * (NROWS / 8);
    for (int jt = 0; jt < NROWS / 8; jt += 16) {
        int jb = j0 + jt;
        bf16x8 bfrag = *reinterpret_cast<const bf16x8*>(bbn_bf + (jb + lr) * BBND + lg * 8);
        f32x4 dot = MFMA(afrag, bfrag, (f32x4){0.f, 0.f, 0.f, 0.f});
        float sj = s[jb + lr];
#pragma unroll
        for (int r = 0; r < 4; ++r) dacc[r] += adj_eval(dot[r], si[r] + sj);
    }
#pragma unroll
    for (int off = 1; off < 16; off <<= 1)
#pragma unroll
        for (int r = 0; r < 4; ++r) dacc[r] += __shfl_xor(dacc[r], off, 64);

    if (lr == 0) {
#pragma unroll
        for (int r = 0; r < 4; ++r) part[w][lg * 4 + r] = dacc[r];
    }
    __syncthreads();
    if (tid < 16) {
        float d = 0.f;
#pragma unroll
        for (int q = 0; q < 8; ++q) d += part[q][tid];
        dinv[ibase + tid] = rsqrtf(d + 1e-8f);
    }
}

// ---------------- fc: gT[c][j] = dinv_j * (cbn@W + b)[j][c], bf16 ----------------
__global__ __launch_bounds__(256) void k_fc(const float* __restrict__ cbn,
                                            const u16* __restrict__ WT,
                                            const float* __restrict__ bvec,
                                            const float* __restrict__ dinv,
                                            u16* __restrict__ gT) {
    int bid = blockIdx.x;            // 1024 = 128 j-tiles * 8 c-tiles
    int cb = bid & 7, jb = bid >> 3;
    int tid = threadIdx.x, w = tid >> 6, l = tid & 63, lg = l >> 4, lr = l & 15;
    int crow = cb * 64 + w * 16;
    int jcol = jb * 64;

    f32x4 acc[4];
#pragma unroll
    for (int f = 0; f < 4; ++f) acc[f] = (f32x4){0.f, 0.f, 0.f, 0.f};

    for (int k0 = 0; k0 < CBND; k0 += 32) {
        bf16x8 afrag = *reinterpret_cast<const bf16x8*>(WT + (crow + lr) * CBND + k0 + lg * 8);
#pragma unroll
        for (int f = 0; f < 4; ++f) {
            const float* src = cbn + (jcol + f * 16 + lr) * CBND + k0 + lg * 8;
            f32x4 v0 = *reinterpret_cast<const f32x4*>(src);
            f32x4 v1 = *reinterpret_cast<const f32x4*>(src + 4);
            bf16x8 bfrag;
#pragma unroll
            for (int e = 0; e < 4; ++e) { bfrag[e] = (__bf16)v0[e]; bfrag[e + 4] = (__bf16)v1[e]; }
            acc[f] = MFMA(afrag, bfrag, acc[f]);
        }
    }
#pragma unroll
    for (int f = 0; f < 4; ++f) {
#pragma unroll
        for (int r = 0; r < 4; ++r) {
            int c = crow + lg * 4 + r;
            int j = jcol + f * 16 + lr;
            float val = acc[f][r] + bvec[c];
            gT[c * NROWS + j] = f2bf(val * dinv[j]);
        }
    }
}

// ---------------- conv: out = sigmoid(dinv_i * sum_j adj_ij * gT[:,j]) ----------------
// Block: 64 i-rows x 128 c-cols, 512 threads (8 waves). Grid 512 (2 blocks/CU).
// Per iter (j-step 64): dbuf'd LDS A (generated adj, swapped-MFMA + cvt_pk) and
// B (gT tile, reg-staged with XOR swizzle). One barrier per iter; everything
// for t+1 is prefetched during t.

// generate + stage for j-tile Tn into buffer WB
#define GEN_STAGE(Tn, WB) { \
    int j0n = (Tn) * JSTEP; \
    u32x4 st0 = *reinterpret_cast<const u32x4*>(gTb + srcfix0 + (long)j0n * 2); \
    u32x4 st1 = *reinterpret_cast<const u32x4*>(gTb + srcfix1 + (long)j0n * 2); \
    int jq = j0n + jh * 32; \
    bf16x8 fj0 = *reinterpret_cast<const bf16x8*>(bbn_bf + (jq + lr) * BBND + lg * 8); \
    bf16x8 fj1 = *reinterpret_cast<const bf16x8*>(bbn_bf + (jq + 16 + lr) * BBND + lg * 8); \
    f32x4 sj0 = *reinterpret_cast<const f32x4*>(s + jq + lg * 4); \
    f32x4 sj1 = *reinterpret_cast<const f32x4*>(s + jq + 16 + lg * 4); \
    f32x4 d0 = MFMA(fj0, fragI, (f32x4){0.f, 0.f, 0.f, 0.f}); \
    f32x4 d1 = MFMA(fj1, fragI, (f32x4){0.f, 0.f, 0.f, 0.f}); \
    u32 p00 = cvtpk(adj_eval(d0[0], si + sj0[0]), adj_eval(d0[1], si + sj0[1])); \
    u32 p01 = cvtpk(adj_eval(d0[2], si + sj0[2]), adj_eval(d0[3], si + sj0[3])); \
    u32 p10 = cvtpk(adj_eval(d1[0], si + sj1[0]), adj_eval(d1[1], si + sj1[1])); \
    u32 p11 = cvtpk(adj_eval(d1[2], si + sj1[2]), adj_eval(d1[3], si + sj1[3])); \
    *reinterpret_cast<u32x2*>(Ab + (WB) * ABUF + bW)      = (u32x2){p00, p01}; \
    *reinterpret_cast<u32x2*>(Ab + (WB) * ABUF + bW + 32) = (u32x2){p10, p11}; \
    *reinterpret_cast<u32x4*>(Bb + (WB) * BBUF + dst0) = st0; \
    *reinterpret_cast<u32x4*>(Bb + (WB) * BBUF + dst1) = st1; \
}

#define CONV_BODY(T, RB, WB) { \
    __syncthreads(); \
    if ((T) + 1 < NT) GEN_STAGE((T) + 1, WB); \
    bf16x8 A0 = *reinterpret_cast<const bf16x8*>(Ab + (RB) * ABUF + bA); \
    bf16x8 A1 = *reinterpret_cast<const bf16x8*>(Ab + (RB) * ABUF + bA + 64); \
    const char* Bbase = Bb + (RB) * BBUF; \
    bf16x8 B00 = *reinterpret_cast<const bf16x8*>(Bbase + bB0); \
    bf16x8 B01 = *reinterpret_cast<const bf16x8*>(Bbase + bB0 + 2048); \
    bf16x8 B02 = *reinterpret_cast<const bf16x8*>(Bbase + bB0 + 4096); \
    bf16x8 B03 = *reinterpret_cast<const bf16x8*>(Bbase + bB0 + 6144); \
    acc0 = MFMA(A0, B00, acc0); \
    acc1 = MFMA(A0, B01, acc1); \
    acc2 = MFMA(A0, B02, acc2); \
    acc3 = MFMA(A0, B03, acc3); \
    bf16x8 B10 = *reinterpret_cast<const bf16x8*>(Bbase + bB1); \
    bf16x8 B11 = *reinterpret_cast<const bf16x8*>(Bbase + bB1 + 2048); \
    bf16x8 B12 = *reinterpret_cast<const bf16x8*>(Bbase + bB1 + 4096); \
    bf16x8 B13 = *reinterpret_cast<const bf16x8*>(Bbase + bB1 + 6144); \
    acc0 = MFMA(A1, B10, acc0); \
    acc1 = MFMA(A1, B11, acc1); \
    acc2 = MFMA(A1, B12, acc2); \
    acc3 = MFMA(A1, B13, acc3); \
}

__global__ __launch_bounds__(512, 4) void k_conv(const u16* __restrict__ bbn_bf,
                                                 const float* __restrict__ s,
                                                 const float* __restrict__ dinv,
                                                 const u16* __restrict__ gT,
                                                 float* __restrict__ out) {
    __shared__ __align__(16) u16 Alds[2][64 * 72];   // padded stride 72 elems (144B)
    __shared__ __align__(16) u16 Blds[2][8192];      // 128c x 64j, XOR-swizzled

    int bx = blockIdx.x;
    // XCD swizzle: XCD x covers 64 consecutive sw ids -> one gT c-slice (2MB, L2-fit)
    int sw = (bx & 7) * 64 + (bx >> 3);
    int cb = sw >> 7;          // 0..3  c-quarter
    int ib = sw & 127;         // 0..127 i-tile
    int ibase = ib * 64;
    int cbase = cb * 128;

    int tid = threadIdx.x;
    int w = tid >> 6, l = tid & 63, lg = l >> 4, lr = l & 15;
    int iq = w & 3;            // i-quad (gen AND acc)
    int ca = w >> 2;           // c-half of block's 128 (64c per wave)
    int jh = w >> 2;           // j-half for gen (reuse ca)

    // hoisted i-fragment for adj gen (B-operand of swapped MFMA)
    bf16x8 fragI = *reinterpret_cast<const bf16x8*>(bbn_bf + (ibase + iq * 16 + lr) * BBND + lg * 8);
    float si = s[ibase + iq * 16 + lr];

    char* Ab = (char*)&Alds[0][0];
    char* Bb = (char*)&Blds[0][0];
    const char* gTb = (const char*)gT;

    // lane addresses (bytes)
    int bA = (iq * 16 + lr) * 144 + lg * 16;                       // A-frag read
    int bW = (iq * 16 + lr) * 144 + jh * 64 + lg * 8;              // gen write
    int bB0 = ca * 8192 + lr * 128 + ((lg * 16) ^ ((l & 7) << 4)); // B-frag read kc=0
    int bB1 = bB0 ^ 64;                                            // kc=1

    // B staging: thread covers 2x16B: logical (c_local, jb) -> swizzled dst
    int cl0 = tid >> 3;                  // 0..63 (q=0); q=1 adds 64
    int jbl = (tid & 7) * 16;
    int swz = ((cl0 & 7) << 4);
    long srcfix0 = (long)(cb * 128 + cl0) * (NROWS * 2) + jbl;
    long srcfix1 = (long)(cb * 128 + 64 + cl0) * (NROWS * 2) + jbl;
    int dst0 = cl0 * 128 + (jbl ^ swz);
    int dst1 = (64 + cl0) * 128 + (jbl ^ swz);

    f32x4 acc0 = (f32x4){0.f, 0.f, 0.f, 0.f};
    f32x4 acc1 = acc0, acc2 = acc0, acc3 = acc0;

    GEN_STAGE(0, 0);

    for (int t2 = 0; t2 < NT; t2 += 2) {
        CONV_BODY(t2, 0, 1);
        CONV_BODY(t2 + 1, 1, 0);
    }

    // epilogue: i = ibase + iq*16 + lg*4 + r ; c = cbase + ca*64 + f*16 + lr
    f32x4 di4 = *reinterpret_cast<const f32x4*>(dinv + ibase + iq * 16 + lg * 4);
    float* orow = out + (long)(ibase + iq * 16 + lg * 4) * CBND + cbase + ca * 64 + lr;
#pragma unroll
    for (int r = 0; r < 4; ++r) {
        float di = di4[r];
        orow[(long)r * CBND +  0] = sigmoidf_fast(acc0[r] * di);
        orow[(long)r * CBND + 16] = sigmoidf_fast(acc1[r] * di);
        orow[(long)r * CBND + 32] = sigmoidf_fast(acc2[r] * di);
        orow[(long)r * CBND + 48] = sigmoidf_fast(acc3[r] * di);
    }
}

extern "C" void kernel_launch(void* const* d_in, const int* in_sizes, int n_in,
                              void* d_out, int out_size, void* d_ws, size_t ws_size,
                              hipStream_t stream) {
    const float* bbn = (const float*)d_in[0];   // [8192,32]
    const float* cbn = (const float*)d_in[1];   // [8192,512]
    const float* W   = (const float*)d_in[2];   // [512,512]
    const float* b   = (const float*)d_in[3];   // [512]
    float* out = (float*)d_out;                 // [8192,512] f32

    char* ws = (char*)d_ws;
    float* s      = (float*)ws;  ws += NROWS * 4;
    float* dinv   = (float*)ws;  ws += NROWS * 4;
    u16* bbn_bf   = (u16*)ws;    ws += NROWS * BBND * 2;
    u16* WT       = (u16*)ws;    ws += CBND * CBND * 2;
    u16* gT       = (u16*)ws;    ws += CBND * NROWS * 2;

    k_prep_rows<<<NROWS / 256, 256, 0, stream>>>(bbn, s, bbn_bf);
    k_prep_wt<<<(CBND * CBND) / 256, 256, 0, stream>>>(W, WT);
    k_deg<<<NROWS / 16, 512, 0, stream>>>(bbn_bf, s, dinv);
    k_fc<<<(NROWS / 64) * (CBND / 64), 256, 0, stream>>>(cbn, WT, b, dinv, gT);
    k_conv<<<(NROWS / 64) * (CBND / 128), 512, 0, stream>>>(bbn_bf, s, dinv, gT, out);
}